// Round 1
// baseline (5870.538 us; speedup 1.0000x reference)
//
#include <hip/hip_runtime.h>
#include <cstdint>
#include <cstddef>

#define N_NODES 16384
#define N_EDGES 65536
#define EN_TOT  (N_EDGES + N_NODES)   // 81920 edges incl self loops
#define FIN 7
#define HC 1600
#define NH 8
#define CHD 200
#define GCN 1600
#define CNN 64
#define BATCH 16
#define GRID 32
#define BN_EPS 1e-5f

// ---------------------------------------------------------------- GAT stage
__global__ __launch_bounds__(256) void k_xlxr(
    const float* __restrict__ x, const float* __restrict__ Wl,
    const float* __restrict__ bl, const float* __restrict__ Wr,
    const float* __restrict__ br, float* __restrict__ xl, float* __restrict__ xr)
{
    int idx = blockIdx.x * 256 + threadIdx.x;          // < N*HC exactly
    int n = idx / HC, f = idx - n * HC;
    float sl = bl[f], sr = br[f];
#pragma unroll
    for (int k = 0; k < FIN; k++) {
        float xv = x[n * FIN + k];
        sl += xv * Wl[k * HC + f];
        sr += xv * Wr[k * HC + f];
    }
    xl[idx] = sl;
    xr[idx] = sr;
}

__global__ __launch_bounds__(256) void k_ea_mean(const float* __restrict__ ea, float* __restrict__ out)
{
    __shared__ float red[256];
    int tid = threadIdx.x;
    float s = 0.f;
    for (int i = tid; i < N_EDGES; i += 256) s += ea[i];
    red[tid] = s;
    __syncthreads();
    for (int o = 128; o > 0; o >>= 1) {
        if (tid < o) red[tid] += red[tid + o];
        __syncthreads();
    }
    if (tid == 0) out[0] = red[0] / (float)N_EDGES;
}

__global__ __launch_bounds__(256) void k_count(const int* __restrict__ dst, int* __restrict__ cnt)
{
    int e = blockIdx.x * 256 + threadIdx.x;
    if (e >= EN_TOT) return;
    int d = (e < N_EDGES) ? dst[e] : (e - N_EDGES);
    atomicAdd(&cnt[d], 1);
}

// single block, 256 threads: 16384 = 256*64
__global__ __launch_bounds__(256) void k_scan(int* __restrict__ cnt, int* __restrict__ offs)
{
    __shared__ int part[256];
    int t = threadIdx.x;
    int base_i = t * 64;
    int s = 0;
    for (int i = 0; i < 64; i++) s += cnt[base_i + i];
    part[t] = s;
    __syncthreads();
    for (int o = 1; o < 256; o <<= 1) {
        int add = (t >= o) ? part[t - o] : 0;
        __syncthreads();
        part[t] += add;
        __syncthreads();
    }
    int run = (t == 0) ? 0 : part[t - 1];
    for (int i = 0; i < 64; i++) {
        int v = cnt[base_i + i];
        offs[base_i + i] = run;
        run += v;
        cnt[base_i + i] = 0;   // reuse as cursor in fill
    }
    if (t == 255) offs[N_NODES] = run;
}

__global__ __launch_bounds__(256) void k_fill(const int* __restrict__ dst,
    const int* __restrict__ offs, int* __restrict__ cur, int* __restrict__ eid)
{
    int e = blockIdx.x * 256 + threadIdx.x;
    if (e >= EN_TOT) return;
    int d = (e < N_EDGES) ? dst[e] : (e - N_EDGES);
    int pos = offs[d] + atomicAdd(&cur[d], 1);
    eid[pos] = e;
}

// one block per edge (512 thr = 8 waves, wave w handles head w)
__global__ __launch_bounds__(512) void k_alpha(
    const float* __restrict__ xl, const float* __restrict__ xr,
    const float* __restrict__ We, const float* __restrict__ att,
    const float* __restrict__ edge_attr, const float* __restrict__ ea_m,
    const int* __restrict__ src, const int* __restrict__ dst,
    float* __restrict__ alpha)
{
    int e = blockIdx.x;
    int tid = threadIdx.x;
    int h = tid >> 6, lane = tid & 63;
    int s, d; float ea;
    if (e < N_EDGES) { s = src[e]; d = dst[e]; ea = edge_attr[e]; }
    else             { s = e - N_EDGES; d = s;  ea = ea_m[0]; }
    const float* xls = xl + (size_t)s * HC + h * CHD;
    const float* xrd = xr + (size_t)d * HC + h * CHD;
    const float* wh  = We + h * CHD;
    const float* ah  = att + h * CHD;
    float sum = 0.f;
    for (int c = lane; c < CHD; c += 64) {
        float m = xls[c] + xrd[c] + ea * wh[c];
        m = (m >= 0.f) ? m : 0.2f * m;
        sum += m * ah[c];
    }
    for (int o = 32; o > 0; o >>= 1) sum += __shfl_down(sum, o);
    if (lane == 0) alpha[(size_t)e * NH + h] = sum;
}

// one block per node: softmax over in-edges + weighted aggregation of xl rows
__global__ __launch_bounds__(256) void k_aggregate(
    const float* __restrict__ xl, const float* __restrict__ alpha,
    const int* __restrict__ offs, const int* __restrict__ eid,
    const int* __restrict__ src, const float* __restrict__ gat_b,
    float* __restrict__ hout)
{
    int n = blockIdx.x, tid = threadIdx.x;
    int beg = offs[n], deg = offs[n + 1] - beg;
    __shared__ float s_amax[NH], s_den[NH];
    __shared__ float s_an[64][NH];
    __shared__ int   s_src[64];
    if (tid < NH) {
        float mx = -1e30f;
        for (int j = 0; j < deg; j++)
            mx = fmaxf(mx, alpha[(size_t)eid[beg + j] * NH + tid]);
        float dn = 0.f;
        for (int j = 0; j < deg; j++)
            dn += expf(alpha[(size_t)eid[beg + j] * NH + tid] - mx);
        s_amax[tid] = mx;
        s_den[tid] = dn;
    }
    __syncthreads();
    float acc[7];
#pragma unroll
    for (int i = 0; i < 7; i++) acc[i] = 0.f;

    for (int base = 0; base < deg; base += 64) {
        int cc = deg - base; if (cc > 64) cc = 64;
        for (int idx = tid; idx < cc; idx += 256) {
            int e = eid[beg + base + idx];
            s_src[idx] = (e < N_EDGES) ? src[e] : (e - N_EDGES);
        }
        for (int idx = tid; idx < cc * NH; idx += 256) {
            int j = idx >> 3, h = idx & 7;
            int e = eid[beg + base + j];
            s_an[j][h] = expf(alpha[(size_t)e * NH + h] - s_amax[h]) / s_den[h];
        }
        __syncthreads();
#pragma unroll
        for (int si = 0; si < 7; si++) {
            int f = tid + (si << 8);
            if (f < HC) {
                int h = f / CHD;
                float a = acc[si];
                for (int j = 0; j < cc; j++)
                    a += s_an[j][h] * xl[(size_t)s_src[j] * HC + f];
                acc[si] = a;
            }
        }
        __syncthreads();
    }
#pragma unroll
    for (int si = 0; si < 7; si++) {
        int f = tid + (si << 8);
        if (f < HC) hout[(size_t)n * HC + f] = acc[si] + gat_b[f];
    }
}

// ---------------------------------------------------------------- BatchNorm1d
__global__ __launch_bounds__(256) void k_bn_partial(
    const float* __restrict__ X, float* __restrict__ bsum, float* __restrict__ bsq,
    int rows, int F)
{
    int f = blockIdx.x * 256 + threadIdx.x;
    if (f >= F) return;
    int chunk = rows / gridDim.y;
    int r0 = blockIdx.y * chunk;
    float s = 0.f, q = 0.f;
    for (int r = r0; r < r0 + chunk; r++) {
        float v = X[(size_t)r * F + f];
        s += v; q += v * v;
    }
    atomicAdd(&bsum[f], s);
    atomicAdd(&bsq[f], q);
}

__global__ __launch_bounds__(256) void k_bn_finalize(
    const float* __restrict__ bsum, const float* __restrict__ bsq,
    const float* __restrict__ g, const float* __restrict__ b,
    float* __restrict__ scale, float* __restrict__ shift, int rows, int F)
{
    int f = blockIdx.x * 256 + threadIdx.x;
    if (f >= F) return;
    float inv = 1.f / (float)rows;
    float mu = bsum[f] * inv;
    float var = bsq[f] * inv - mu * mu;
    float sc = g[f] * rsqrtf(var + BN_EPS);
    scale[f] = sc;
    shift[f] = b[f] - mu * sc;
}

// mode: 0 none, 1 lrelu(0.01), 2 relu
__global__ __launch_bounds__(256) void k_bn_apply(
    float* __restrict__ X, const float* __restrict__ scale,
    const float* __restrict__ shift, int total, int F, int mode)
{
    int idx = blockIdx.x * 256 + threadIdx.x;
    if (idx >= total) return;
    int f = idx % F;
    float v = X[idx] * scale[f] + shift[f];
    if (mode == 1) v = (v >= 0.f) ? v : 0.01f * v;
    else if (mode == 2) v = fmaxf(v, 0.f);
    X[idx] = v;
}

// ---------------------------------------------------------------- f32 GEMM
// C[M,Nn] = A[M,K] @ B[K,Nn] + bias, optional relu. 128x128 tile, 8x8/thread.
__global__ __launch_bounds__(256) void k_gemm(
    const float* __restrict__ A, const float* __restrict__ B,
    const float* __restrict__ bias, float* __restrict__ C,
    int M, int K, int Nn, int relu)
{
    __shared__ float As[16][132];
    __shared__ float Bs[16][132];
    int tid = threadIdx.x;
    int tx = tid & 15, ty = tid >> 4;
    int row0 = blockIdx.y * 128, col0 = blockIdx.x * 128;
    float acc[8][8];
#pragma unroll
    for (int i = 0; i < 8; i++)
#pragma unroll
        for (int j = 0; j < 8; j++) acc[i][j] = 0.f;

    for (int kk = 0; kk < K; kk += 16) {
#pragma unroll
        for (int i = 0; i < 2; i++) {
            int id = tid + (i << 8);
            int ar = id >> 2, ac = (id & 3) << 2;
            float4 av = *(const float4*)(A + (size_t)(row0 + ar) * K + kk + ac);
            As[ac + 0][ar] = av.x; As[ac + 1][ar] = av.y;
            As[ac + 2][ar] = av.z; As[ac + 3][ar] = av.w;
            int brr = id >> 5, bcc = (id & 31) << 2;
            float4 bv;
            if (col0 + bcc < Nn)
                bv = *(const float4*)(B + (size_t)(kk + brr) * Nn + col0 + bcc);
            else
                bv = make_float4(0.f, 0.f, 0.f, 0.f);
            *(float4*)&Bs[brr][bcc] = bv;
        }
        __syncthreads();
#pragma unroll
        for (int k = 0; k < 16; k++) {
            float a[8], b[8];
            *(float4*)&a[0] = *(const float4*)&As[k][ty * 8];
            *(float4*)&a[4] = *(const float4*)&As[k][ty * 8 + 4];
            *(float4*)&b[0] = *(const float4*)&Bs[k][tx * 8];
            *(float4*)&b[4] = *(const float4*)&Bs[k][tx * 8 + 4];
#pragma unroll
            for (int i = 0; i < 8; i++)
#pragma unroll
                for (int j = 0; j < 8; j++)
                    acc[i][j] += a[i] * b[j];
        }
        __syncthreads();
    }
#pragma unroll
    for (int i = 0; i < 8; i++) {
        size_t r = row0 + ty * 8 + i;
#pragma unroll
        for (int j = 0; j < 8; j++) {
            int c = col0 + tx * 8 + j;
            if (c < Nn) {
                float v = acc[i][j] + bias[c];
                if (relu) v = fmaxf(v, 0.f);
                C[r * Nn + c] = v;
            }
        }
    }
}

// ---------------------------------------------------------------- CNN stage
__global__ __launch_bounds__(256) void k_transpose(const float* __restrict__ p, float* __restrict__ img)
{
    int o = blockIdx.x * 256 + threadIdx.x;        // [B,64,32,32] order
    if (o >= BATCH * CNN * 1024) return;
    int sp = o & 1023;
    int bc = o >> 10;
    int c = bc & 63, b = bc >> 6;
    img[o] = p[((size_t)(b * 1024 + sp)) * CNN + c];
}

__global__ __launch_bounds__(256) void k_conv5(
    const float* __restrict__ in, const float* __restrict__ w,
    const float* __restrict__ bias, float* __restrict__ out, int Cin, int Cout)
{
    int idx = blockIdx.x * 256 + threadIdx.x;
    if (idx >= BATCH * Cout * 1024) return;
    int x = idx & 31, y = (idx >> 5) & 31;
    int bc = idx >> 10;
    int co = bc % Cout, b = bc / Cout;
    const float* wp = w + (size_t)co * Cin * 25;
    float acc = bias[co];
    for (int ci = 0; ci < Cin; ci++) {
        const float* ip = in + (((size_t)b * Cin + ci) << 10);
        const float* wc = wp + ci * 25;
#pragma unroll
        for (int ky = 0; ky < 5; ky++) {
            int iy = y + ky - 2;
            if ((unsigned)iy < 32u) {
#pragma unroll
                for (int kx = 0; kx < 5; kx++) {
                    int ix = x + kx - 2;
                    if ((unsigned)ix < 32u)
                        acc += ip[(iy << 5) + ix] * wc[ky * 5 + kx];
                }
            }
        }
    }
    out[idx] = acc;
}

// BatchNorm2d stats: one block per channel (reduce over B*H*W = 16384)
__global__ __launch_bounds__(256) void k_bnc_stats(
    const float* __restrict__ in, const float* __restrict__ g,
    const float* __restrict__ be, float* __restrict__ scale,
    float* __restrict__ shift, int C)
{
    __shared__ float rs[256], rq[256];
    int c = blockIdx.x, tid = threadIdx.x;
    float s = 0.f, q = 0.f;
    for (int i = tid; i < BATCH * 1024; i += 256) {
        int b = i >> 10, p = i & 1023;
        float v = in[(((size_t)b * C + c) << 10) + p];
        s += v; q += v * v;
    }
    rs[tid] = s; rq[tid] = q;
    __syncthreads();
    for (int o = 128; o > 0; o >>= 1) {
        if (tid < o) { rs[tid] += rs[tid + o]; rq[tid] += rq[tid + o]; }
        __syncthreads();
    }
    if (tid == 0) {
        float inv = 1.f / (float)(BATCH * 1024);
        float mu = rs[0] * inv;
        float var = rq[0] * inv - mu * mu;
        float sc = g[c] * rsqrtf(var + BN_EPS);
        scale[c] = sc;
        shift[c] = be[c] - mu * sc;
    }
}

__global__ __launch_bounds__(256) void k_bnc_apply(
    float* __restrict__ X, const float* __restrict__ scale,
    const float* __restrict__ shift, int C)
{
    int idx = blockIdx.x * 256 + threadIdx.x;
    if (idx >= BATCH * C * 1024) return;
    int c = (idx >> 10) % C;
    float v = X[idx] * scale[c] + shift[c];
    X[idx] = fmaxf(v, 0.f);
}

// ---------------------------------------------------------------- launch
extern "C" void kernel_launch(void* const* d_in, const int* in_sizes, int n_in,
                              void* d_out, int out_size, void* d_ws, size_t ws_size,
                              hipStream_t stream)
{
    const float* x   = (const float*)d_in[0];
    const float* ea  = (const float*)d_in[1];
    const float* Wl  = (const float*)d_in[2];
    const float* bl  = (const float*)d_in[3];
    const float* Wr  = (const float*)d_in[4];
    const float* br  = (const float*)d_in[5];
    const float* We  = (const float*)d_in[6];
    const float* att = (const float*)d_in[7];
    const float* gat_b = (const float*)d_in[8];
    const float* bn1_g = (const float*)d_in[9];
    const float* bn1_b = (const float*)d_in[10];
    const float* W1 = (const float*)d_in[11];
    const float* b1 = (const float*)d_in[12];
    const float* bn2_g = (const float*)d_in[13];
    const float* bn2_b = (const float*)d_in[14];
    const float* W2 = (const float*)d_in[15];
    const float* b2 = (const float*)d_in[16];
    const float* Wp = (const float*)d_in[17];
    const float* bp = (const float*)d_in[18];
    const float* cw1 = (const float*)d_in[19]; const float* cb1 = (const float*)d_in[20];
    const float* g1  = (const float*)d_in[21]; const float* be1 = (const float*)d_in[22];
    const float* cw2 = (const float*)d_in[23]; const float* cb2 = (const float*)d_in[24];
    const float* g2  = (const float*)d_in[25]; const float* be2 = (const float*)d_in[26];
    const float* cw3 = (const float*)d_in[27]; const float* cb3 = (const float*)d_in[28];
    const float* g3  = (const float*)d_in[29]; const float* be3 = (const float*)d_in[30];
    const float* cw4 = (const float*)d_in[31]; const float* cb4 = (const float*)d_in[32];
    const int* src = (const int*)d_in[33];
    const int* dst = (const int*)d_in[34];
    float* out = (float*)d_out;

    // ---- workspace layout (floats) ----
    const size_t SZ_BIG = (size_t)N_NODES * HC;        // 26,214,400
    float* fws   = (float*)d_ws;
    float* bufA  = fws;                                // xl, later h2
    float* bufB  = bufA + SZ_BIG;                      // xr, later h, later h3
    float* alpha = bufB + SZ_BIG;                      // EN_TOT*8
    float* pbuf  = alpha + (size_t)EN_TOT * NH;        // N*64
    float* imgA  = pbuf + (size_t)N_NODES * CNN;       // 2,097,152
    float* imgB  = imgA + (size_t)BATCH * 128 * 1024;  // 2,097,152
    float* ea_m  = imgB + (size_t)BATCH * 128 * 1024;  // 16
    float* bn_sum = ea_m + 16;                         // 1600
    float* bn_sq  = bn_sum + HC;                       // 1600 (contiguous w/ bn_sum)
    float* bn_sc  = bn_sq + HC;                        // 1600
    float* bn_sh  = bn_sc + HC;                        // 1600
    int*   cnt  = (int*)(bn_sh + HC + 64);             // N
    int*   offs = cnt + N_NODES;                       // N+1
    int*   eid  = offs + N_NODES + 1 + 63;             // EN_TOT

    // ---- GAT ----
    hipMemsetAsync(cnt, 0, N_NODES * sizeof(int), stream);
    k_ea_mean<<<1, 256, 0, stream>>>(ea, ea_m);
    k_xlxr<<<(N_NODES * HC) / 256, 256, 0, stream>>>(x, Wl, bl, Wr, br, bufA, bufB);
    k_count<<<(EN_TOT + 255) / 256, 256, 0, stream>>>(dst, cnt);
    k_scan<<<1, 256, 0, stream>>>(cnt, offs);
    k_fill<<<(EN_TOT + 255) / 256, 256, 0, stream>>>(dst, offs, cnt, eid);
    k_alpha<<<EN_TOT, 512, 0, stream>>>(bufA, bufB, We, att, ea, ea_m, src, dst, alpha);
    k_aggregate<<<N_NODES, 256, 0, stream>>>(bufA, alpha, offs, eid, src, gat_b, bufB);

    // ---- BN1 + lrelu(0.01) on bufB ----
    hipMemsetAsync(bn_sum, 0, 2 * HC * sizeof(float), stream);
    k_bn_partial<<<dim3(7, 32), 256, 0, stream>>>(bufB, bn_sum, bn_sq, N_NODES, HC);
    k_bn_finalize<<<7, 256, 0, stream>>>(bn_sum, bn_sq, bn1_g, bn1_b, bn_sc, bn_sh, N_NODES, HC);
    k_bn_apply<<<(N_NODES * HC) / 256, 256, 0, stream>>>(bufB, bn_sc, bn_sh, N_NODES * HC, HC, 1);

    // ---- GEMM1 + BN2 + relu ----
    k_gemm<<<dim3(13, 128), 256, 0, stream>>>(bufB, W1, b1, bufA, N_NODES, HC, GCN, 0);
    hipMemsetAsync(bn_sum, 0, 2 * HC * sizeof(float), stream);
    k_bn_partial<<<dim3(7, 32), 256, 0, stream>>>(bufA, bn_sum, bn_sq, N_NODES, GCN);
    k_bn_finalize<<<7, 256, 0, stream>>>(bn_sum, bn_sq, bn2_g, bn2_b, bn_sc, bn_sh, N_NODES, GCN);
    k_bn_apply<<<(N_NODES * GCN) / 256, 256, 0, stream>>>(bufA, bn_sc, bn_sh, N_NODES * GCN, GCN, 2);

    // ---- GEMM2 + relu (fused), GEMM3 projection ----
    k_gemm<<<dim3(13, 128), 256, 0, stream>>>(bufA, W2, b2, bufB, N_NODES, GCN, GCN, 1);
    k_gemm<<<dim3(1, 128), 256, 0, stream>>>(bufB, Wp, bp, pbuf, N_NODES, GCN, CNN, 0);

    // ---- to NCHW, conv stack ----
    k_transpose<<<(BATCH * CNN * 1024) / 256, 256, 0, stream>>>(pbuf, imgA);

    k_conv5<<<(BATCH * 64 * 1024) / 256, 256, 0, stream>>>(imgA, cw1, cb1, imgB, 64, 64);
    k_bnc_stats<<<64, 256, 0, stream>>>(imgB, g1, be1, bn_sc, bn_sh, 64);
    k_bnc_apply<<<(BATCH * 64 * 1024) / 256, 256, 0, stream>>>(imgB, bn_sc, bn_sh, 64);

    k_conv5<<<(BATCH * 128 * 1024) / 256, 256, 0, stream>>>(imgB, cw2, cb2, imgA, 64, 128);
    k_bnc_stats<<<128, 256, 0, stream>>>(imgA, g2, be2, bn_sc, bn_sh, 128);
    k_bnc_apply<<<(BATCH * 128 * 1024) / 256, 256, 0, stream>>>(imgA, bn_sc, bn_sh, 128);

    k_conv5<<<(BATCH * 64 * 1024) / 256, 256, 0, stream>>>(imgA, cw3, cb3, imgB, 128, 64);
    k_bnc_stats<<<64, 256, 0, stream>>>(imgB, g3, be3, bn_sc, bn_sh, 64);
    k_bnc_apply<<<(BATCH * 64 * 1024) / 256, 256, 0, stream>>>(imgB, bn_sc, bn_sh, 64);

    k_conv5<<<(BATCH * 6 * 1024) / 256, 256, 0, stream>>>(imgB, cw4, cb4, out, 64, 6);
    (void)in_sizes; (void)n_in; (void)out_size; (void)ws_size;
}

// Round 2
// 2068.868 us; speedup vs baseline: 2.8376x; 2.8376x over previous
//
#include <hip/hip_runtime.h>
#include <cstdint>
#include <cstddef>

#define N_NODES 16384
#define N_EDGES 65536
#define EN_TOT  (N_EDGES + N_NODES)
#define FIN 7
#define HC 1600
#define NH 8
#define CHD 200
#define GCN 1600
#define CNN 64
#define BATCH 16
#define BN_EPS 1e-5f

typedef unsigned short ushort_t;
typedef __attribute__((ext_vector_type(8))) short s8frag;
typedef __attribute__((ext_vector_type(4))) float f32x4;

__device__ __forceinline__ ushort_t f2bf(float f) {
    unsigned u = __float_as_uint(f);
    unsigned r = (u + 0x7FFFu + ((u >> 16) & 1u)) >> 16;
    return (ushort_t)r;
}

__device__ __forceinline__ void gload16(const void* g, void* l) {
    __builtin_amdgcn_global_load_lds((const __attribute__((address_space(1))) void*)g,
                                     (__attribute__((address_space(3))) void*)l, 16, 0, 0);
}

// ---------------------------------------------------------------- GAT stage
__global__ __launch_bounds__(256) void k_xlxr(
    const float* __restrict__ x, const float* __restrict__ Wl,
    const float* __restrict__ bl, const float* __restrict__ Wr,
    const float* __restrict__ br, float* __restrict__ xl, float* __restrict__ xr)
{
    int idx = blockIdx.x * 256 + threadIdx.x;
    int n = idx / HC, f = idx - n * HC;
    float sl = bl[f], sr = br[f];
#pragma unroll
    for (int k = 0; k < FIN; k++) {
        float xv = x[n * FIN + k];
        sl += xv * Wl[k * HC + f];
        sr += xv * Wr[k * HC + f];
    }
    xl[idx] = sl;
    xr[idx] = sr;
}

__global__ __launch_bounds__(256) void k_ea_mean(const float* __restrict__ ea, float* __restrict__ out)
{
    __shared__ float red[256];
    int tid = threadIdx.x;
    float s = 0.f;
    for (int i = tid; i < N_EDGES; i += 256) s += ea[i];
    red[tid] = s;
    __syncthreads();
    for (int o = 128; o > 0; o >>= 1) {
        if (tid < o) red[tid] += red[tid + o];
        __syncthreads();
    }
    if (tid == 0) out[0] = red[0] / (float)N_EDGES;
}

__global__ __launch_bounds__(256) void k_count(const int* __restrict__ dst, int* __restrict__ cnt)
{
    int e = blockIdx.x * 256 + threadIdx.x;
    if (e >= EN_TOT) return;
    int d = (e < N_EDGES) ? dst[e] : (e - N_EDGES);
    atomicAdd(&cnt[d], 1);
}

__global__ __launch_bounds__(256) void k_scan(int* __restrict__ cnt, int* __restrict__ offs)
{
    __shared__ int part[256];
    int t = threadIdx.x;
    int base_i = t * 64;
    int s = 0;
    for (int i = 0; i < 64; i++) s += cnt[base_i + i];
    part[t] = s;
    __syncthreads();
    for (int o = 1; o < 256; o <<= 1) {
        int add = (t >= o) ? part[t - o] : 0;
        __syncthreads();
        part[t] += add;
        __syncthreads();
    }
    int run = (t == 0) ? 0 : part[t - 1];
    for (int i = 0; i < 64; i++) {
        int v = cnt[base_i + i];
        offs[base_i + i] = run;
        run += v;
        cnt[base_i + i] = 0;
    }
    if (t == 255) offs[N_NODES] = run;
}

__global__ __launch_bounds__(256) void k_fill(const int* __restrict__ dst,
    const int* __restrict__ offs, int* __restrict__ cur, int* __restrict__ eid)
{
    int e = blockIdx.x * 256 + threadIdx.x;
    if (e >= EN_TOT) return;
    int d = (e < N_EDGES) ? dst[e] : (e - N_EDGES);
    int pos = offs[d] + atomicAdd(&cur[d], 1);
    eid[pos] = e;
}

__global__ __launch_bounds__(512) void k_alpha(
    const float* __restrict__ xl, const float* __restrict__ xr,
    const float* __restrict__ We, const float* __restrict__ att,
    const float* __restrict__ edge_attr, const float* __restrict__ ea_m,
    const int* __restrict__ src, const int* __restrict__ dst,
    float* __restrict__ alpha)
{
    int e = blockIdx.x;
    int tid = threadIdx.x;
    int h = tid >> 6, lane = tid & 63;
    int s, d; float ea;
    if (e < N_EDGES) { s = src[e]; d = dst[e]; ea = edge_attr[e]; }
    else             { s = e - N_EDGES; d = s;  ea = ea_m[0]; }
    const float* xls = xl + (size_t)s * HC + h * CHD;
    const float* xrd = xr + (size_t)d * HC + h * CHD;
    const float* wh  = We + h * CHD;
    const float* ah  = att + h * CHD;
    float sum = 0.f;
    for (int c = lane; c < CHD; c += 64) {
        float m = xls[c] + xrd[c] + ea * wh[c];
        m = (m >= 0.f) ? m : 0.2f * m;
        sum += m * ah[c];
    }
    for (int o = 32; o > 0; o >>= 1) sum += __shfl_down(sum, o);
    if (lane == 0) alpha[(size_t)e * NH + h] = sum;
}

__global__ __launch_bounds__(256) void k_aggregate(
    const float* __restrict__ xl, const float* __restrict__ alpha,
    const int* __restrict__ offs, const int* __restrict__ eid,
    const int* __restrict__ src, const float* __restrict__ gat_b,
    float* __restrict__ hout)
{
    int n = blockIdx.x, tid = threadIdx.x;
    int beg = offs[n], deg = offs[n + 1] - beg;
    __shared__ float s_amax[NH], s_den[NH];
    __shared__ float s_an[64][NH];
    __shared__ int   s_src[64];
    if (tid < NH) {
        float mx = -1e30f;
        for (int j = 0; j < deg; j++)
            mx = fmaxf(mx, alpha[(size_t)eid[beg + j] * NH + tid]);
        float dn = 0.f;
        for (int j = 0; j < deg; j++)
            dn += expf(alpha[(size_t)eid[beg + j] * NH + tid] - mx);
        s_amax[tid] = mx;
        s_den[tid] = dn;
    }
    __syncthreads();
    float acc[7];
#pragma unroll
    for (int i = 0; i < 7; i++) acc[i] = 0.f;

    for (int base = 0; base < deg; base += 64) {
        int cc = deg - base; if (cc > 64) cc = 64;
        for (int idx = tid; idx < cc; idx += 256) {
            int e = eid[beg + base + idx];
            s_src[idx] = (e < N_EDGES) ? src[e] : (e - N_EDGES);
        }
        for (int idx = tid; idx < cc * NH; idx += 256) {
            int j = idx >> 3, h = idx & 7;
            int e = eid[beg + base + j];
            s_an[j][h] = expf(alpha[(size_t)e * NH + h] - s_amax[h]) / s_den[h];
        }
        __syncthreads();
#pragma unroll
        for (int si = 0; si < 7; si++) {
            int f = tid + (si << 8);
            if (f < HC) {
                int h = f / CHD;
                float a = acc[si];
                for (int j = 0; j < cc; j++)
                    a += s_an[j][h] * xl[(size_t)s_src[j] * HC + f];
                acc[si] = a;
            }
        }
        __syncthreads();
    }
#pragma unroll
    for (int si = 0; si < 7; si++) {
        int f = tid + (si << 8);
        if (f < HC) hout[(size_t)n * HC + f] = acc[si] + gat_b[f];
    }
}

// ---------------------------------------------------------------- BatchNorm (col-major features)
__global__ __launch_bounds__(256) void k_bn_partial(
    const float* __restrict__ X, float* __restrict__ bsum, float* __restrict__ bsq,
    int rows, int F)
{
    int f = blockIdx.x * 256 + threadIdx.x;
    if (f >= F) return;
    int chunk = rows / gridDim.y;
    int r0 = blockIdx.y * chunk;
    float s = 0.f, q = 0.f;
    for (int r = r0; r < r0 + chunk; r++) {
        float v = X[(size_t)r * F + f];
        s += v; q += v * v;
    }
    atomicAdd(&bsum[f], s);
    atomicAdd(&bsq[f], q);
}

__global__ __launch_bounds__(256) void k_bn_finalize(
    const float* __restrict__ bsum, const float* __restrict__ bsq,
    const float* __restrict__ g, const float* __restrict__ b,
    float* __restrict__ scale, float* __restrict__ shift, int rows, int F)
{
    int f = blockIdx.x * 256 + threadIdx.x;
    if (f >= F) return;
    float inv = 1.f / (float)rows;
    float mu = bsum[f] * inv;
    float var = bsq[f] * inv - mu * mu;
    float sc = g[f] * rsqrtf(var + BN_EPS);
    scale[f] = sc;
    shift[f] = b[f] - mu * sc;
}

// mode: 1 lrelu(0.01), 2 relu  — reads f32, writes bf16
__global__ __launch_bounds__(256) void k_bn_apply_bf(
    const float* __restrict__ X, ushort_t* __restrict__ Y,
    const float* __restrict__ scale, const float* __restrict__ shift,
    int total, int F, int mode)
{
    int idx = blockIdx.x * 256 + threadIdx.x;
    if (idx >= total) return;
    int f = idx % F;
    float v = X[idx] * scale[f] + shift[f];
    if (mode == 1) v = (v >= 0.f) ? v : 0.01f * v;
    else v = fmaxf(v, 0.f);
    Y[idx] = f2bf(v);
}

// ---------------------------------------------------------------- weight prep
// W [Kdim][Ndim] f32 -> BT [Ndim(+pad)][Kdim] bf16.  grid (Ndim/32, Kdim/32), block 256
__global__ __launch_bounds__(256) void k_wt(
    const float* __restrict__ W, ushort_t* __restrict__ BT, int Kdim, int Ndim)
{
    __shared__ float t[32][33];
    int tx = threadIdx.x & 31, ty = threadIdx.x >> 5;
    int n0 = blockIdx.x * 32, k0 = blockIdx.y * 32;
#pragma unroll
    for (int i = 0; i < 4; i++)
        t[ty + i * 8][tx] = W[(size_t)(k0 + ty + i * 8) * Ndim + n0 + tx];
    __syncthreads();
#pragma unroll
    for (int i = 0; i < 4; i++)
        BT[(size_t)(n0 + ty + i * 8) * Kdim + k0 + tx] = f2bf(t[tx][ty + i * 8]);
}

// conv w [Cout][Cin][25] f32 -> out bf16 [Cout][p*Cin+ci], p=ky*5+kx
__global__ __launch_bounds__(256) void k_cwt(
    const float* __restrict__ w, ushort_t* __restrict__ out, int Cout, int Cin)
{
    int idx = blockIdx.x * 256 + threadIdx.x;
    if (idx >= Cout * Cin * 25) return;
    int cin25 = Cin * 25;
    int co = idx / cin25;
    int rem = idx - co * cin25;
    int p = rem / Cin;
    int ci = rem - p * Cin;
    out[idx] = f2bf(w[(size_t)(co * Cin + ci) * 25 + p]);
}

// ---------------------------------------------------------------- im2col (NHWC bf16, 8ch chunks)
// in [16384][C] -> col [16384][25*C], col index = p*C+ci,  p=ky*5+kx
__global__ __launch_bounds__(256) void k_im2col(
    const uint4* __restrict__ in, uint4* __restrict__ col, int nc8, int nc8shift)
{
    int idx = blockIdx.x * 256 + threadIdx.x;   // total = 16384*25*nc8 exactly
    int ci8 = idx & (nc8 - 1);
    int t = idx >> nc8shift;
    int p = t % 25;
    int pix = t / 25;
    int kx = p - (p / 5) * 5, ky = p / 5;
    int x = pix & 31, y = (pix >> 5) & 31, b = pix >> 10;
    int iy = y + ky - 2, ix = x + kx - 2;
    uint4 v = make_uint4(0u, 0u, 0u, 0u);
    if ((unsigned)iy < 32u && (unsigned)ix < 32u)
        v = in[(size_t)(((b << 5) + iy) * 32 + ix) * nc8 + ci8];
    col[(size_t)(pix * 25 + p) * nc8 + ci8] = v;
}

// ---------------------------------------------------------------- MFMA GEMM
// C[M,N] = A[M,K](bf16) @ BT[Npad,K](bf16)^T + bias.
// 128x128 tile, 4 waves (2x2), each wave 64x64 via 4x4 mfma_f32_16x16x32_bf16.
// out_mode: 0 = f32 C[row*ldc+col]; 1 = bf16 relu; 2 = f32 NCHW (conv4)
__global__ __launch_bounds__(256) void k_mgemm(
    const ushort_t* __restrict__ A, const ushort_t* __restrict__ BT,
    const float* __restrict__ bias, float* __restrict__ Cf, ushort_t* __restrict__ Cb,
    int K, int Nvalid, int ldc, int relu, int out_mode)
{
    __shared__ __align__(16) ushort_t As[128 * 32];
    __shared__ __align__(16) ushort_t Bs[128 * 32];
    int tid = threadIdx.x;
    int lane = tid & 63;
    int wid = tid >> 6;
    int wy = wid >> 1, wx = wid & 1;
    int row0 = blockIdx.y * 128, col0 = blockIdx.x * 128;

    f32x4 acc[4][4];
#pragma unroll
    for (int i = 0; i < 4; i++)
#pragma unroll
        for (int j = 0; j < 4; j++) acc[i][j] = (f32x4)0.f;

    int r0 = tid >> 2;             // 0..63
    int c0 = (tid & 3) * 8;        // element offset in k within 32-chunk
    const ushort_t* Ag = A + (size_t)row0 * K + c0;
    const ushort_t* Bg = BT + (size_t)col0 * K + c0;
    char* lA0 = (char*)As + tid * 16;
    char* lA1 = (char*)As + (tid + 256) * 16;
    char* lB0 = (char*)Bs + tid * 16;
    char* lB1 = (char*)Bs + (tid + 256) * 16;

    int am = lane & 15, aq = (lane >> 4) * 8;
    int aoff0 = (wy * 64 + am) * 32 + aq;
    int boff0 = (wx * 64 + am) * 32 + aq;

    for (int kk = 0; kk < K; kk += 32) {
        __syncthreads();
        gload16(Ag + (size_t)r0 * K + kk, lA0);
        gload16(Ag + (size_t)(r0 + 64) * K + kk, lA1);
        gload16(Bg + (size_t)r0 * K + kk, lB0);
        gload16(Bg + (size_t)(r0 + 64) * K + kk, lB1);
        __syncthreads();

        s8frag a[4], b[4];
#pragma unroll
        for (int mi = 0; mi < 4; mi++)
            a[mi] = *(const s8frag*)&As[aoff0 + mi * 16 * 32];
#pragma unroll
        for (int ni = 0; ni < 4; ni++)
            b[ni] = *(const s8frag*)&Bs[boff0 + ni * 16 * 32];
#pragma unroll
        for (int mi = 0; mi < 4; mi++)
#pragma unroll
            for (int ni = 0; ni < 4; ni++)
                acc[mi][ni] = __builtin_amdgcn_mfma_f32_16x16x32_bf16(
                    a[mi], b[ni], acc[mi][ni], 0, 0, 0);
    }

    int lc = lane & 15, lr4 = (lane >> 4) * 4;
#pragma unroll
    for (int ni = 0; ni < 4; ni++) {
        int col = col0 + wx * 64 + ni * 16 + lc;
        if (col >= Nvalid) continue;
        float bv = bias[col];
#pragma unroll
        for (int mi = 0; mi < 4; mi++) {
#pragma unroll
            for (int r = 0; r < 4; r++) {
                int row = row0 + wy * 64 + mi * 16 + lr4 + r;
                float v = acc[mi][ni][r] + bv;
                if (relu) v = fmaxf(v, 0.f);
                if (out_mode == 0) {
                    Cf[(size_t)row * ldc + col] = v;
                } else if (out_mode == 1) {
                    Cb[(size_t)row * ldc + col] = f2bf(v);
                } else {
                    int b = row >> 10, sp = row & 1023;
                    Cf[(size_t)((b * 6 + col) << 10) + sp] = v;
                }
            }
        }
    }
}

// ---------------------------------------------------------------- launch
extern "C" void kernel_launch(void* const* d_in, const int* in_sizes, int n_in,
                              void* d_out, int out_size, void* d_ws, size_t ws_size,
                              hipStream_t stream)
{
    const float* x   = (const float*)d_in[0];
    const float* ea  = (const float*)d_in[1];
    const float* Wl  = (const float*)d_in[2];
    const float* bl  = (const float*)d_in[3];
    const float* Wr  = (const float*)d_in[4];
    const float* br  = (const float*)d_in[5];
    const float* We  = (const float*)d_in[6];
    const float* att = (const float*)d_in[7];
    const float* gat_b = (const float*)d_in[8];
    const float* bn1_g = (const float*)d_in[9];
    const float* bn1_b = (const float*)d_in[10];
    const float* W1 = (const float*)d_in[11];
    const float* b1 = (const float*)d_in[12];
    const float* bn2_g = (const float*)d_in[13];
    const float* bn2_b = (const float*)d_in[14];
    const float* W2 = (const float*)d_in[15];
    const float* b2 = (const float*)d_in[16];
    const float* Wp = (const float*)d_in[17];
    const float* bp = (const float*)d_in[18];
    const float* cw1 = (const float*)d_in[19]; const float* cb1 = (const float*)d_in[20];
    const float* g1  = (const float*)d_in[21]; const float* be1 = (const float*)d_in[22];
    const float* cw2 = (const float*)d_in[23]; const float* cb2 = (const float*)d_in[24];
    const float* g2  = (const float*)d_in[25]; const float* be2 = (const float*)d_in[26];
    const float* cw3 = (const float*)d_in[27]; const float* cb3 = (const float*)d_in[28];
    const float* g3  = (const float*)d_in[29]; const float* be3 = (const float*)d_in[30];
    const float* cw4 = (const float*)d_in[31]; const float* cb4 = (const float*)d_in[32];
    const int* src = (const int*)d_in[33];
    const int* dst = (const int*)d_in[34];
    float* out = (float*)d_out;

    // ---- workspace layout (bytes) ----
    const size_t SZ_REGION = (size_t)N_NODES * HC * 4;         // 104,857,600 B
    char* ws = (char*)d_ws;
    char* regA = ws;                                            // xl f32 | abuf16+a2buf16 | h3_16 | col
    char* regB = regA + SZ_REGION;                              // xr f32 | h f32 | gemm1 f32 | pb16/convf/inN
    char* wbase = regB + SZ_REGION;
    ushort_t* W1T  = (ushort_t*)wbase;                          // [1664][1600]
    ushort_t* W2T  = W1T + (size_t)1664 * 1600;
    ushort_t* WpT  = W2T + (size_t)1664 * 1600;                 // [128][1600]
    ushort_t* c1T  = WpT + (size_t)128 * 1600;                  // [128][1600]
    ushort_t* c2T  = c1T + (size_t)128 * 1600;                  // [128][1600]
    ushort_t* c3T  = c2T + (size_t)128 * 1600;                  // [128][3200]
    ushort_t* c4T  = c3T + (size_t)128 * 3200;                  // [128][1600]
    float* alpha   = (float*)(c4T + (size_t)128 * 1600);        // EN_TOT*8
    float* ea_m    = alpha + (size_t)EN_TOT * NH;
    float* bn_sum  = ea_m + 64;
    float* bn_sq   = bn_sum + HC;
    float* bn_sc   = bn_sq + HC;
    float* bn_sh   = bn_sc + HC;
    int* cnt  = (int*)(bn_sh + HC + 64);
    int* offs = cnt + N_NODES;
    int* eid  = offs + N_NODES + 1 + 63;

    // region A views
    float*    xl      = (float*)regA;
    ushort_t* abuf16  = (ushort_t*)regA;                        // 52.4 MB
    ushort_t* a2buf16 = (ushort_t*)(regA + SZ_REGION / 2);      // 52.4 MB
    ushort_t* h3_16   = (ushort_t*)regA;                        // over abuf16
    ushort_t* colbuf  = (ushort_t*)regA;                        // up to 104.9 MB
    // region B views
    float*    xr      = (float*)regB;
    float*    hbuf    = (float*)regB;                           // GAT out, then GEMM1 f32 out
    ushort_t* pb16    = (ushort_t*)regB;                        // [16384][64]
    float*    convf   = (float*)(regB + (4 << 20));             // up to 8.4 MB
    ushort_t* in2     = (ushort_t*)(regB + (16 << 20));         // [16384][64]
    ushort_t* in3     = (ushort_t*)(regB + (24 << 20));         // [16384][128]
    ushort_t* in4     = (ushort_t*)(regB + (32 << 20));         // [16384][64]

    // ---- weight prep (independent of activations) ----
    k_wt<<<dim3(50, 50), 256, 0, stream>>>(W1, W1T, 1600, 1600);
    hipMemsetAsync(W1T + (size_t)1600 * 1600, 0, (size_t)64 * 1600 * 2, stream);
    k_wt<<<dim3(50, 50), 256, 0, stream>>>(W2, W2T, 1600, 1600);
    hipMemsetAsync(W2T + (size_t)1600 * 1600, 0, (size_t)64 * 1600 * 2, stream);
    k_wt<<<dim3(2, 50), 256, 0, stream>>>(Wp, WpT, 1600, 64);
    hipMemsetAsync(WpT + (size_t)64 * 1600, 0, (size_t)64 * 1600 * 2, stream);
    k_cwt<<<(64 * 64 * 25 + 255) / 256, 256, 0, stream>>>(cw1, c1T, 64, 64);
    hipMemsetAsync(c1T + (size_t)64 * 1600, 0, (size_t)64 * 1600 * 2, stream);
    k_cwt<<<(128 * 64 * 25 + 255) / 256, 256, 0, stream>>>(cw2, c2T, 128, 64);
    k_cwt<<<(64 * 128 * 25 + 255) / 256, 256, 0, stream>>>(cw3, c3T, 64, 128);
    hipMemsetAsync(c3T + (size_t)64 * 3200, 0, (size_t)64 * 3200 * 2, stream);
    k_cwt<<<(6 * 64 * 25 + 255) / 256, 256, 0, stream>>>(cw4, c4T, 6, 64);
    hipMemsetAsync(c4T + (size_t)6 * 1600, 0, (size_t)122 * 1600 * 2, stream);

    // ---- GAT ----
    hipMemsetAsync(cnt, 0, N_NODES * sizeof(int), stream);
    k_ea_mean<<<1, 256, 0, stream>>>(ea, ea_m);
    k_xlxr<<<(N_NODES * HC) / 256, 256, 0, stream>>>(x, Wl, bl, Wr, br, xl, xr);
    k_count<<<(EN_TOT + 255) / 256, 256, 0, stream>>>(dst, cnt);
    k_scan<<<1, 256, 0, stream>>>(cnt, offs);
    k_fill<<<(EN_TOT + 255) / 256, 256, 0, stream>>>(dst, offs, cnt, eid);
    k_alpha<<<EN_TOT, 512, 0, stream>>>(xl, xr, We, att, ea, ea_m, src, dst, alpha);
    k_aggregate<<<N_NODES, 256, 0, stream>>>(xl, alpha, offs, eid, src, gat_b, hbuf);

    // ---- BN1 + lrelu -> bf16 ----
    hipMemsetAsync(bn_sum, 0, 2 * HC * sizeof(float), stream);
    k_bn_partial<<<dim3(7, 32), 256, 0, stream>>>(hbuf, bn_sum, bn_sq, N_NODES, HC);
    k_bn_finalize<<<7, 256, 0, stream>>>(bn_sum, bn_sq, bn1_g, bn1_b, bn_sc, bn_sh, N_NODES, HC);
    k_bn_apply_bf<<<(N_NODES * HC) / 256, 256, 0, stream>>>(hbuf, abuf16, bn_sc, bn_sh, N_NODES * HC, HC, 1);

    // ---- GEMM1 (f32 out for BN stats) ----
    k_mgemm<<<dim3(13, 128), 256, 0, stream>>>(abuf16, W1T, b1, hbuf, (ushort_t*)nullptr,
                                               1600, 1600, 1600, 0, 0);
    hipMemsetAsync(bn_sum, 0, 2 * HC * sizeof(float), stream);
    k_bn_partial<<<dim3(7, 32), 256, 0, stream>>>(hbuf, bn_sum, bn_sq, N_NODES, GCN);
    k_bn_finalize<<<7, 256, 0, stream>>>(bn_sum, bn_sq, bn2_g, bn2_b, bn_sc, bn_sh, N_NODES, GCN);
    k_bn_apply_bf<<<(N_NODES * GCN) / 256, 256, 0, stream>>>(hbuf, a2buf16, bn_sc, bn_sh, N_NODES * GCN, GCN, 2);

    // ---- GEMM2 (relu, bf16 out) ----
    k_mgemm<<<dim3(13, 128), 256, 0, stream>>>(a2buf16, W2T, b2, (float*)nullptr, h3_16,
                                               1600, 1600, 1600, 1, 1);
    // ---- projection GEMM (bf16 out, NHWC) ----
    k_mgemm<<<dim3(1, 128), 256, 0, stream>>>(h3_16, WpT, bp, (float*)nullptr, pb16,
                                              1600, 64, 64, 0, 1);

    // ---- conv1 ----
    k_im2col<<<(16384 * 25 * 8) / 256, 256, 0, stream>>>((const uint4*)pb16, (uint4*)colbuf, 8, 3);
    k_mgemm<<<dim3(1, 128), 256, 0, stream>>>(colbuf, c1T, cb1, convf, (ushort_t*)nullptr,
                                              1600, 64, 64, 0, 0);
    hipMemsetAsync(bn_sum, 0, 2 * HC * sizeof(float), stream);
    k_bn_partial<<<dim3(1, 32), 256, 0, stream>>>(convf, bn_sum, bn_sq, 16384, 64);
    k_bn_finalize<<<1, 256, 0, stream>>>(bn_sum, bn_sq, g1, be1, bn_sc, bn_sh, 16384, 64);
    k_bn_apply_bf<<<(16384 * 64) / 256, 256, 0, stream>>>(convf, in2, bn_sc, bn_sh, 16384 * 64, 64, 2);

    // ---- conv2 ----
    k_im2col<<<(16384 * 25 * 8) / 256, 256, 0, stream>>>((const uint4*)in2, (uint4*)colbuf, 8, 3);
    k_mgemm<<<dim3(1, 128), 256, 0, stream>>>(colbuf, c2T, cb2, convf, (ushort_t*)nullptr,
                                              1600, 128, 128, 0, 0);
    hipMemsetAsync(bn_sum, 0, 2 * HC * sizeof(float), stream);
    k_bn_partial<<<dim3(1, 32), 256, 0, stream>>>(convf, bn_sum, bn_sq, 16384, 128);
    k_bn_finalize<<<1, 256, 0, stream>>>(bn_sum, bn_sq, g2, be2, bn_sc, bn_sh, 16384, 128);
    k_bn_apply_bf<<<(16384 * 128) / 256, 256, 0, stream>>>(convf, in3, bn_sc, bn_sh, 16384 * 128, 128, 2);

    // ---- conv3 ----
    k_im2col<<<(16384 * 25 * 16) / 256, 256, 0, stream>>>((const uint4*)in3, (uint4*)colbuf, 16, 4);
    k_mgemm<<<dim3(1, 128), 256, 0, stream>>>(colbuf, c3T, cb3, convf, (ushort_t*)nullptr,
                                              3200, 64, 64, 0, 0);
    hipMemsetAsync(bn_sum, 0, 2 * HC * sizeof(float), stream);
    k_bn_partial<<<dim3(1, 32), 256, 0, stream>>>(convf, bn_sum, bn_sq, 16384, 64);
    k_bn_finalize<<<1, 256, 0, stream>>>(bn_sum, bn_sq, g3, be3, bn_sc, bn_sh, 16384, 64);
    k_bn_apply_bf<<<(16384 * 64) / 256, 256, 0, stream>>>(convf, in4, bn_sc, bn_sh, 16384 * 64, 64, 2);

    // ---- conv4 (NCHW f32 out) ----
    k_im2col<<<(16384 * 25 * 8) / 256, 256, 0, stream>>>((const uint4*)in4, (uint4*)colbuf, 8, 3);
    k_mgemm<<<dim3(1, 128), 256, 0, stream>>>(colbuf, c4T, cb4, out, (ushort_t*)nullptr,
                                              1600, 6, 6, 0, 2);

    (void)in_sizes; (void)n_in; (void)out_size; (void)ws_size;
}

// Round 3
// 1480.350 us; speedup vs baseline: 3.9656x; 1.3976x over previous
//
#include <hip/hip_runtime.h>
#include <cstdint>
#include <cstddef>

#define N_NODES 16384
#define N_EDGES 65536
#define EN_TOT  (N_EDGES + N_NODES)
#define FIN 7
#define HC 1600
#define NH 8
#define CHD 200
#define GCN 1600
#define CNN 64
#define BATCH 16
#define BN_EPS 1e-5f

typedef unsigned short ushort_t;
typedef __attribute__((ext_vector_type(8))) short s8frag;
typedef __attribute__((ext_vector_type(4))) float f32x4;

__device__ __forceinline__ ushort_t f2bf(float f) {
    unsigned u = __float_as_uint(f);
    unsigned r = (u + 0x7FFFu + ((u >> 16) & 1u)) >> 16;
    return (ushort_t)r;
}
__device__ __forceinline__ float bf2f(ushort_t u) {
    return __uint_as_float(((unsigned)u) << 16);
}

__device__ __forceinline__ void gload16(const void* g, void* l) {
    __builtin_amdgcn_global_load_lds((const __attribute__((address_space(1))) void*)g,
                                     (__attribute__((address_space(3))) void*)l, 16, 0, 0);
}

// ---------------------------------------------------------------- GAT stage
__global__ __launch_bounds__(256) void k_xlxr(
    const float* __restrict__ x, const float* __restrict__ Wl,
    const float* __restrict__ bl, const float* __restrict__ Wr,
    const float* __restrict__ br, ushort_t* __restrict__ xl, ushort_t* __restrict__ xr)
{
    int idx = blockIdx.x * 256 + threadIdx.x;
    int n = idx / HC, f = idx - n * HC;
    float sl = bl[f], sr = br[f];
#pragma unroll
    for (int k = 0; k < FIN; k++) {
        float xv = x[n * FIN + k];
        sl += xv * Wl[k * HC + f];
        sr += xv * Wr[k * HC + f];
    }
    xl[idx] = f2bf(sl);
    xr[idx] = f2bf(sr);
}

__global__ __launch_bounds__(256) void k_ea_mean(const float* __restrict__ ea, float* __restrict__ out)
{
    __shared__ float red[256];
    int tid = threadIdx.x;
    float s = 0.f;
    for (int i = tid; i < N_EDGES; i += 256) s += ea[i];
    red[tid] = s;
    __syncthreads();
    for (int o = 128; o > 0; o >>= 1) {
        if (tid < o) red[tid] += red[tid + o];
        __syncthreads();
    }
    if (tid == 0) out[0] = red[0] / (float)N_EDGES;
}

__global__ __launch_bounds__(256) void k_count(const int* __restrict__ dst, int* __restrict__ cnt)
{
    int e = blockIdx.x * 256 + threadIdx.x;
    if (e >= EN_TOT) return;
    int d = (e < N_EDGES) ? dst[e] : (e - N_EDGES);
    atomicAdd(&cnt[d], 1);
}

__global__ __launch_bounds__(256) void k_scan(int* __restrict__ cnt, int* __restrict__ offs)
{
    __shared__ int part[256];
    int t = threadIdx.x;
    int base_i = t * 64;
    int s = 0;
    for (int i = 0; i < 64; i++) s += cnt[base_i + i];
    part[t] = s;
    __syncthreads();
    for (int o = 1; o < 256; o <<= 1) {
        int add = (t >= o) ? part[t - o] : 0;
        __syncthreads();
        part[t] += add;
        __syncthreads();
    }
    int run = (t == 0) ? 0 : part[t - 1];
    for (int i = 0; i < 64; i++) {
        int v = cnt[base_i + i];
        offs[base_i + i] = run;
        run += v;
        cnt[base_i + i] = 0;
    }
    if (t == 255) offs[N_NODES] = run;
}

__global__ __launch_bounds__(256) void k_fill(const int* __restrict__ dst,
    const int* __restrict__ offs, int* __restrict__ cur, int* __restrict__ eid)
{
    int e = blockIdx.x * 256 + threadIdx.x;
    if (e >= EN_TOT) return;
    int d = (e < N_EDGES) ? dst[e] : (e - N_EDGES);
    int pos = offs[d] + atomicAdd(&cur[d], 1);
    eid[pos] = e;
}

// one block per edge, wave h handles head h; bf16 xl/xr with ushort4 loads
__global__ __launch_bounds__(512) void k_alpha(
    const ushort_t* __restrict__ xl, const ushort_t* __restrict__ xr,
    const float* __restrict__ We, const float* __restrict__ att,
    const float* __restrict__ edge_attr, const float* __restrict__ ea_m,
    const int* __restrict__ src, const int* __restrict__ dst,
    float* __restrict__ alpha)
{
    int e = blockIdx.x;
    int tid = threadIdx.x;
    int h = tid >> 6, lane = tid & 63;
    int s, d; float ea;
    if (e < N_EDGES) { s = src[e]; d = dst[e]; ea = edge_attr[e]; }
    else             { s = e - N_EDGES; d = s;  ea = ea_m[0]; }
    float sum = 0.f;
    if (lane < 50) {
        int c4 = lane * 4;
        const ushort4* xls = (const ushort4*)(xl + (size_t)s * HC + h * CHD + c4);
        const ushort4* xrd = (const ushort4*)(xr + (size_t)d * HC + h * CHD + c4);
        ushort4 av = *xls;
        ushort4 bv = *xrd;
        const float* wh = We + h * CHD + c4;
        const float* ah = att + h * CHD + c4;
        float xa[4] = {bf2f(av.x), bf2f(av.y), bf2f(av.z), bf2f(av.w)};
        float xb[4] = {bf2f(bv.x), bf2f(bv.y), bf2f(bv.z), bf2f(bv.w)};
#pragma unroll
        for (int i = 0; i < 4; i++) {
            float m = xa[i] + xb[i] + ea * wh[i];
            m = (m >= 0.f) ? m : 0.2f * m;
            sum += m * ah[i];
        }
    }
    for (int o = 32; o > 0; o >>= 1) sum += __shfl_down(sum, o);
    if (lane == 0) alpha[(size_t)e * NH + h] = sum;
}

__global__ __launch_bounds__(256) void k_aggregate(
    const ushort_t* __restrict__ xl, const float* __restrict__ alpha,
    const int* __restrict__ offs, const int* __restrict__ eid,
    const int* __restrict__ src, const float* __restrict__ gat_b,
    ushort_t* __restrict__ hout)
{
    int n = blockIdx.x, tid = threadIdx.x;
    int beg = offs[n], deg = offs[n + 1] - beg;
    __shared__ float s_amax[NH], s_den[NH];
    __shared__ float s_an[64][NH];
    __shared__ int   s_src[64];
    if (tid < NH) {
        float mx = -1e30f;
        for (int j = 0; j < deg; j++)
            mx = fmaxf(mx, alpha[(size_t)eid[beg + j] * NH + tid]);
        float dn = 0.f;
        for (int j = 0; j < deg; j++)
            dn += expf(alpha[(size_t)eid[beg + j] * NH + tid] - mx);
        s_amax[tid] = mx;
        s_den[tid] = dn;
    }
    __syncthreads();
    float acc[7];
#pragma unroll
    for (int i = 0; i < 7; i++) acc[i] = 0.f;

    for (int base = 0; base < deg; base += 64) {
        int cc = deg - base; if (cc > 64) cc = 64;
        for (int idx = tid; idx < cc; idx += 256) {
            int e = eid[beg + base + idx];
            s_src[idx] = (e < N_EDGES) ? src[e] : (e - N_EDGES);
        }
        for (int idx = tid; idx < cc * NH; idx += 256) {
            int j = idx >> 3, h = idx & 7;
            int e = eid[beg + base + j];
            s_an[j][h] = expf(alpha[(size_t)e * NH + h] - s_amax[h]) / s_den[h];
        }
        __syncthreads();
#pragma unroll
        for (int si = 0; si < 7; si++) {
            int f = tid + (si << 8);
            if (f < HC) {
                int h = f / CHD;
                float a = acc[si];
                for (int j = 0; j < cc; j++)
                    a += s_an[j][h] * bf2f(xl[(size_t)s_src[j] * HC + f]);
                acc[si] = a;
            }
        }
        __syncthreads();
    }
#pragma unroll
    for (int si = 0; si < 7; si++) {
        int f = tid + (si << 8);
        if (f < HC) hout[(size_t)n * HC + f] = f2bf(acc[si] + gat_b[f]);
    }
}

// ---------------------------------------------------------------- BatchNorm helpers
__global__ __launch_bounds__(256) void k_bn_partial_bf(
    const ushort_t* __restrict__ X, float* __restrict__ bsum, float* __restrict__ bsq,
    int rows, int F)
{
    int f = blockIdx.x * 256 + threadIdx.x;
    if (f >= F) return;
    int chunk = rows / gridDim.y;
    int r0 = blockIdx.y * chunk;
    float s = 0.f, q = 0.f;
    for (int r = r0; r < r0 + chunk; r++) {
        float v = bf2f(X[(size_t)r * F + f]);
        s += v; q += v * v;
    }
    atomicAdd(&bsum[f], s);
    atomicAdd(&bsq[f], q);
}

__global__ __launch_bounds__(256) void k_bn_finalize(
    const float* __restrict__ bsum, const float* __restrict__ bsq,
    const float* __restrict__ g, const float* __restrict__ b,
    float* __restrict__ scale, float* __restrict__ shift, int rows, int F)
{
    int f = blockIdx.x * 256 + threadIdx.x;
    if (f >= F) return;
    float inv = 1.f / (float)rows;
    float mu = bsum[f] * inv;
    float var = bsq[f] * inv - mu * mu;
    float sc = g[f] * rsqrtf(var + BN_EPS);
    scale[f] = sc;
    shift[f] = b[f] - mu * sc;
}

// bf16 in -> bf16 out.  mode: 1 lrelu(0.01), 2 relu
__global__ __launch_bounds__(256) void k_bn_apply_bb(
    const ushort_t* __restrict__ X, ushort_t* __restrict__ Y,
    const float* __restrict__ scale, const float* __restrict__ shift,
    int total, int F, int mode)
{
    int idx = blockIdx.x * 256 + threadIdx.x;
    if (idx >= total) return;
    int f = idx % F;
    float v = bf2f(X[idx]) * scale[f] + shift[f];
    if (mode == 1) v = (v >= 0.f) ? v : 0.01f * v;
    else v = fmaxf(v, 0.f);
    Y[idx] = f2bf(v);
}

// ---------------------------------------------------------------- weight prep
__global__ __launch_bounds__(256) void k_wt(
    const float* __restrict__ W, ushort_t* __restrict__ BT, int Kdim, int Ndim)
{
    __shared__ float t[32][33];
    int tx = threadIdx.x & 31, ty = threadIdx.x >> 5;
    int n0 = blockIdx.x * 32, k0 = blockIdx.y * 32;
#pragma unroll
    for (int i = 0; i < 4; i++)
        t[ty + i * 8][tx] = W[(size_t)(k0 + ty + i * 8) * Ndim + n0 + tx];
    __syncthreads();
#pragma unroll
    for (int i = 0; i < 4; i++)
        BT[(size_t)(n0 + ty + i * 8) * Kdim + k0 + tx] = f2bf(t[tx][ty + i * 8]);
}

__global__ __launch_bounds__(256) void k_cwt(
    const float* __restrict__ w, ushort_t* __restrict__ out, int Cout, int Cin)
{
    int idx = blockIdx.x * 256 + threadIdx.x;
    if (idx >= Cout * Cin * 25) return;
    int cin25 = Cin * 25;
    int co = idx / cin25;
    int rem = idx - co * cin25;
    int p = rem / Cin;
    int ci = rem - p * Cin;
    out[idx] = f2bf(w[(size_t)(co * Cin + ci) * 25 + p]);
}

// ---------------------------------------------------------------- im2col (NHWC bf16, 8ch chunks)
__global__ __launch_bounds__(256) void k_im2col(
    const uint4* __restrict__ in, uint4* __restrict__ col, int nc8, int nc8shift)
{
    int idx = blockIdx.x * 256 + threadIdx.x;
    int ci8 = idx & (nc8 - 1);
    int t = idx >> nc8shift;
    int p = t % 25;
    int pix = t / 25;
    int kx = p - (p / 5) * 5, ky = p / 5;
    int x = pix & 31, y = (pix >> 5) & 31, b = pix >> 10;
    int iy = y + ky - 2, ix = x + kx - 2;
    uint4 v = make_uint4(0u, 0u, 0u, 0u);
    if ((unsigned)iy < 32u && (unsigned)ix < 32u)
        v = in[(size_t)(((b << 5) + iy) * 32 + ix) * nc8 + ci8];
    col[(size_t)(pix * 25 + p) * nc8 + ci8] = v;
}

// ---------------------------------------------------------------- MFMA GEMM
// C[M,N] = A[M,K](bf16) @ BT[Npad,K](bf16)^T + bias.
// out_mode: 0 f32; 1 bf16; 2 f32 NCHW (conv4).  bsum/bsq: optional fused BN stats (pre-relu).
__global__ __launch_bounds__(256) void k_mgemm(
    const ushort_t* __restrict__ A, const ushort_t* __restrict__ BT,
    const float* __restrict__ bias, float* __restrict__ Cf, ushort_t* __restrict__ Cb,
    float* __restrict__ bsum, float* __restrict__ bsq,
    int K, int Nvalid, int ldc, int relu, int out_mode)
{
    __shared__ __align__(16) ushort_t As[128 * 32];
    __shared__ __align__(16) ushort_t Bs[128 * 32];
    int tid = threadIdx.x;
    int lane = tid & 63;
    int wid = tid >> 6;
    int wy = wid >> 1, wx = wid & 1;
    int row0 = blockIdx.y * 128, col0 = blockIdx.x * 128;

    f32x4 acc[4][4];
#pragma unroll
    for (int i = 0; i < 4; i++)
#pragma unroll
        for (int j = 0; j < 4; j++) acc[i][j] = (f32x4)0.f;

    int r0 = tid >> 2;
    int c0 = (tid & 3) * 8;
    const ushort_t* Ag = A + (size_t)row0 * K + c0;
    const ushort_t* Bg = BT + (size_t)col0 * K + c0;
    char* lA0 = (char*)As + tid * 16;
    char* lA1 = (char*)As + (tid + 256) * 16;
    char* lB0 = (char*)Bs + tid * 16;
    char* lB1 = (char*)Bs + (tid + 256) * 16;

    int am = lane & 15, aq = (lane >> 4) * 8;
    int aoff0 = (wy * 64 + am) * 32 + aq;
    int boff0 = (wx * 64 + am) * 32 + aq;

    for (int kk = 0; kk < K; kk += 32) {
        __syncthreads();
        gload16(Ag + (size_t)r0 * K + kk, lA0);
        gload16(Ag + (size_t)(r0 + 64) * K + kk, lA1);
        gload16(Bg + (size_t)r0 * K + kk, lB0);
        gload16(Bg + (size_t)(r0 + 64) * K + kk, lB1);
        __syncthreads();

        s8frag a[4], b[4];
#pragma unroll
        for (int mi = 0; mi < 4; mi++)
            a[mi] = *(const s8frag*)&As[aoff0 + mi * 16 * 32];
#pragma unroll
        for (int ni = 0; ni < 4; ni++)
            b[ni] = *(const s8frag*)&Bs[boff0 + ni * 16 * 32];
#pragma unroll
        for (int mi = 0; mi < 4; mi++)
#pragma unroll
            for (int ni = 0; ni < 4; ni++)
                acc[mi][ni] = __builtin_amdgcn_mfma_f32_16x16x32_bf16(
                    a[mi], b[ni], acc[mi][ni], 0, 0, 0);
    }

    int lc = lane & 15, lr4 = (lane >> 4) * 4;
#pragma unroll
    for (int ni = 0; ni < 4; ni++) {
        int col = col0 + wx * 64 + ni * 16 + lc;
        bool valid = col < Nvalid;
        float bv = valid ? bias[col] : 0.f;
        float s = 0.f, q = 0.f;
#pragma unroll
        for (int mi = 0; mi < 4; mi++) {
#pragma unroll
            for (int r = 0; r < 4; r++) {
                int row = row0 + wy * 64 + mi * 16 + lr4 + r;
                float v = acc[mi][ni][r] + bv;
                s += v; q += v * v;
                float vo = relu ? fmaxf(v, 0.f) : v;
                if (valid) {
                    if (out_mode == 0) Cf[(size_t)row * ldc + col] = vo;
                    else if (out_mode == 1) Cb[(size_t)row * ldc + col] = f2bf(vo);
                    else {
                        int bb = row >> 10, sp = row & 1023;
                        Cf[(size_t)((bb * 6 + col) << 10) + sp] = vo;
                    }
                }
            }
        }
        if (bsum != nullptr && valid) {
            s += __shfl_xor(s, 16); s += __shfl_xor(s, 32);
            q += __shfl_xor(q, 16); q += __shfl_xor(q, 32);
            if ((lane >> 4) == 0) {
                atomicAdd(&bsum[col], s);
                atomicAdd(&bsq[col], q);
            }
        }
    }
}

// ---------------------------------------------------------------- launch
extern "C" void kernel_launch(void* const* d_in, const int* in_sizes, int n_in,
                              void* d_out, int out_size, void* d_ws, size_t ws_size,
                              hipStream_t stream)
{
    const float* x   = (const float*)d_in[0];
    const float* ea  = (const float*)d_in[1];
    const float* Wl  = (const float*)d_in[2];
    const float* bl  = (const float*)d_in[3];
    const float* Wr  = (const float*)d_in[4];
    const float* br  = (const float*)d_in[5];
    const float* We  = (const float*)d_in[6];
    const float* att = (const float*)d_in[7];
    const float* gat_b = (const float*)d_in[8];
    const float* bn1_g = (const float*)d_in[9];
    const float* bn1_b = (const float*)d_in[10];
    const float* W1 = (const float*)d_in[11];
    const float* b1 = (const float*)d_in[12];
    const float* bn2_g = (const float*)d_in[13];
    const float* bn2_b = (const float*)d_in[14];
    const float* W2 = (const float*)d_in[15];
    const float* b2 = (const float*)d_in[16];
    const float* Wp = (const float*)d_in[17];
    const float* bp = (const float*)d_in[18];
    const float* cw1 = (const float*)d_in[19]; const float* cb1 = (const float*)d_in[20];
    const float* g1  = (const float*)d_in[21]; const float* be1 = (const float*)d_in[22];
    const float* cw2 = (const float*)d_in[23]; const float* cb2 = (const float*)d_in[24];
    const float* g2  = (const float*)d_in[25]; const float* be2 = (const float*)d_in[26];
    const float* cw3 = (const float*)d_in[27]; const float* cb3 = (const float*)d_in[28];
    const float* g3  = (const float*)d_in[29]; const float* be3 = (const float*)d_in[30];
    const float* cw4 = (const float*)d_in[31]; const float* cb4 = (const float*)d_in[32];
    const int* src = (const int*)d_in[33];
    const int* dst = (const int*)d_in[34];
    float* out = (float*)d_out;

    // ---- workspace layout ----
    const size_t SZ_REGION = (size_t)N_NODES * HC * 4;         // 104,857,600 B
    const size_t HALF = SZ_REGION / 2;                          // 52,428,800 B
    char* ws = (char*)d_ws;
    char* regA = ws;
    char* regB = regA + SZ_REGION;
    char* wbase = regB + SZ_REGION;
    ushort_t* W1T  = (ushort_t*)wbase;                          // [1664][1600]
    ushort_t* W2T  = W1T + (size_t)1664 * 1600;
    ushort_t* WpT  = W2T + (size_t)1664 * 1600;                 // [128][1600]
    ushort_t* c1T  = WpT + (size_t)128 * 1600;
    ushort_t* c2T  = c1T + (size_t)128 * 1600;
    ushort_t* c3T  = c2T + (size_t)128 * 1600;                  // [128][3200]
    ushort_t* c4T  = c3T + (size_t)128 * 3200;
    float* alpha   = (float*)(c4T + (size_t)128 * 1600);
    float* ea_m    = alpha + (size_t)EN_TOT * NH;
    float* bn_sum  = ea_m + 64;
    float* bn_sq   = bn_sum + HC;
    float* bn_sc   = bn_sq + HC;
    float* bn_sh   = bn_sc + HC;
    int* cnt  = (int*)(bn_sh + HC + 64);
    int* offs = cnt + N_NODES;
    int* eid  = offs + N_NODES + 1 + 63;

    // region A views
    ushort_t* xl16    = (ushort_t*)regA;                        // [0,52M)
    ushort_t* xr16    = (ushort_t*)(regA + HALF);               // [52M,105M)
    ushort_t* abuf16  = (ushort_t*)regA;                        // BN1 out (over xl16, after aggregate)
    ushort_t* a2buf16 = (ushort_t*)(regA + HALF);               // BN2 out (over xr16)
    ushort_t* pb16    = (ushort_t*)regA;                        // [16384][64] proj out (over abuf16, after GEMM2... careful below)
    ushort_t* c1out   = (ushort_t*)(regA + (2u << 20));
    ushort_t* in2     = (ushort_t*)(regA + (4u << 20));
    ushort_t* c2out   = (ushort_t*)(regA + (6u << 20));
    ushort_t* in3     = (ushort_t*)(regA + (10u << 20));
    ushort_t* c3out   = (ushort_t*)(regA + (14u << 20));
    ushort_t* in4     = (ushort_t*)(regA + (16u << 20));
    // region B views
    ushort_t* hb16    = (ushort_t*)regB;                        // GAT out bf16 [0,52M)
    ushort_t* g1b16   = (ushort_t*)regB;                        // GEMM1 out (over hb16)
    ushort_t* h3_16   = (ushort_t*)regB;                        // GEMM2 out (over g1b16)
    ushort_t* colbuf  = (ushort_t*)regB;                        // im2col buffer (up to 105M)

    // ---- weight prep ----
    k_wt<<<dim3(50, 50), 256, 0, stream>>>(W1, W1T, 1600, 1600);
    hipMemsetAsync(W1T + (size_t)1600 * 1600, 0, (size_t)64 * 1600 * 2, stream);
    k_wt<<<dim3(50, 50), 256, 0, stream>>>(W2, W2T, 1600, 1600);
    hipMemsetAsync(W2T + (size_t)1600 * 1600, 0, (size_t)64 * 1600 * 2, stream);
    k_wt<<<dim3(2, 50), 256, 0, stream>>>(Wp, WpT, 1600, 64);
    hipMemsetAsync(WpT + (size_t)64 * 1600, 0, (size_t)64 * 1600 * 2, stream);
    k_cwt<<<(64 * 64 * 25 + 255) / 256, 256, 0, stream>>>(cw1, c1T, 64, 64);
    hipMemsetAsync(c1T + (size_t)64 * 1600, 0, (size_t)64 * 1600 * 2, stream);
    k_cwt<<<(128 * 64 * 25 + 255) / 256, 256, 0, stream>>>(cw2, c2T, 128, 64);
    k_cwt<<<(64 * 128 * 25 + 255) / 256, 256, 0, stream>>>(cw3, c3T, 64, 128);
    hipMemsetAsync(c3T + (size_t)64 * 3200, 0, (size_t)64 * 3200 * 2, stream);
    k_cwt<<<(6 * 64 * 25 + 255) / 256, 256, 0, stream>>>(cw4, c4T, 6, 64);
    hipMemsetAsync(c4T + (size_t)6 * 1600, 0, (size_t)122 * 1600 * 2, stream);

    // ---- GAT ----
    hipMemsetAsync(cnt, 0, N_NODES * sizeof(int), stream);
    k_ea_mean<<<1, 256, 0, stream>>>(ea, ea_m);
    k_xlxr<<<(N_NODES * HC) / 256, 256, 0, stream>>>(x, Wl, bl, Wr, br, xl16, xr16);
    k_count<<<(EN_TOT + 255) / 256, 256, 0, stream>>>(dst, cnt);
    k_scan<<<1, 256, 0, stream>>>(cnt, offs);
    k_fill<<<(EN_TOT + 255) / 256, 256, 0, stream>>>(dst, offs, cnt, eid);
    k_alpha<<<EN_TOT, 512, 0, stream>>>(xl16, xr16, We, att, ea, ea_m, src, dst, alpha);
    k_aggregate<<<N_NODES, 256, 0, stream>>>(xl16, alpha, offs, eid, src, gat_b, hb16);

    // ---- BN1 (bf16 stats) + lrelu -> abuf16 (over xl16, dead now) ----
    hipMemsetAsync(bn_sum, 0, 2 * HC * sizeof(float), stream);
    k_bn_partial_bf<<<dim3(7, 32), 256, 0, stream>>>(hb16, bn_sum, bn_sq, N_NODES, HC);
    k_bn_finalize<<<7, 256, 0, stream>>>(bn_sum, bn_sq, bn1_g, bn1_b, bn_sc, bn_sh, N_NODES, HC);
    k_bn_apply_bb<<<(N_NODES * HC) / 256, 256, 0, stream>>>(hb16, abuf16, bn_sc, bn_sh, N_NODES * HC, HC, 1);

    // ---- GEMM1 (bf16 out + fused BN stats) ----
    hipMemsetAsync(bn_sum, 0, 2 * HC * sizeof(float), stream);
    k_mgemm<<<dim3(13, 128), 256, 0, stream>>>(abuf16, W1T, b1, (float*)nullptr, g1b16,
                                               bn_sum, bn_sq, 1600, 1600, 1600, 0, 1);
    k_bn_finalize<<<7, 256, 0, stream>>>(bn_sum, bn_sq, bn2_g, bn2_b, bn_sc, bn_sh, N_NODES, GCN);
    k_bn_apply_bb<<<(N_NODES * GCN) / 256, 256, 0, stream>>>(g1b16, a2buf16, bn_sc, bn_sh, N_NODES * GCN, GCN, 2);

    // ---- GEMM2 (relu, bf16 out) ----
    k_mgemm<<<dim3(13, 128), 256, 0, stream>>>(a2buf16, W2T, b2, (float*)nullptr, h3_16,
                                               (float*)nullptr, (float*)nullptr, 1600, 1600, 1600, 1, 1);
    // ---- projection GEMM: writes pb16 into regA[0,2M) (abuf16 dead after GEMM1) ----
    k_mgemm<<<dim3(1, 128), 256, 0, stream>>>(h3_16, WpT, bp, (float*)nullptr, pb16,
                                              (float*)nullptr, (float*)nullptr, 1600, 64, 64, 0, 1);

    // ---- conv1 ----
    k_im2col<<<(16384 * 25 * 8) / 256, 256, 0, stream>>>((const uint4*)pb16, (uint4*)colbuf, 8, 3);
    hipMemsetAsync(bn_sum, 0, 2 * HC * sizeof(float), stream);
    k_mgemm<<<dim3(1, 128), 256, 0, stream>>>(colbuf, c1T, cb1, (float*)nullptr, c1out,
                                              bn_sum, bn_sq, 1600, 64, 64, 0, 1);
    k_bn_finalize<<<1, 256, 0, stream>>>(bn_sum, bn_sq, g1, be1, bn_sc, bn_sh, 16384, 64);
    k_bn_apply_bb<<<(16384 * 64) / 256, 256, 0, stream>>>(c1out, in2, bn_sc, bn_sh, 16384 * 64, 64, 2);

    // ---- conv2 ----
    k_im2col<<<(16384 * 25 * 8) / 256, 256, 0, stream>>>((const uint4*)in2, (uint4*)colbuf, 8, 3);
    hipMemsetAsync(bn_sum, 0, 2 * HC * sizeof(float), stream);
    k_mgemm<<<dim3(1, 128), 256, 0, stream>>>(colbuf, c2T, cb2, (float*)nullptr, c2out,
                                              bn_sum, bn_sq, 1600, 128, 128, 0, 1);
    k_bn_finalize<<<1, 256, 0, stream>>>(bn_sum, bn_sq, g2, be2, bn_sc, bn_sh, 16384, 128);
    k_bn_apply_bb<<<(16384 * 128) / 256, 256, 0, stream>>>(c2out, in3, bn_sc, bn_sh, 16384 * 128, 128, 2);

    // ---- conv3 ----
    k_im2col<<<(16384 * 25 * 16) / 256, 256, 0, stream>>>((const uint4*)in3, (uint4*)colbuf, 16, 4);
    hipMemsetAsync(bn_sum, 0, 2 * HC * sizeof(float), stream);
    k_mgemm<<<dim3(1, 128), 256, 0, stream>>>(colbuf, c3T, cb3, (float*)nullptr, c3out,
                                              bn_sum, bn_sq, 3200, 64, 64, 0, 1);
    k_bn_finalize<<<1, 256, 0, stream>>>(bn_sum, bn_sq, g3, be3, bn_sc, bn_sh, 16384, 64);
    k_bn_apply_bb<<<(16384 * 64) / 256, 256, 0, stream>>>(c3out, in4, bn_sc, bn_sh, 16384 * 64, 64, 2);

    // ---- conv4 (NCHW f32 out) ----
    k_im2col<<<(16384 * 25 * 8) / 256, 256, 0, stream>>>((const uint4*)in4, (uint4*)colbuf, 8, 3);
    k_mgemm<<<dim3(1, 128), 256, 0, stream>>>(colbuf, c4T, cb4, out, (ushort_t*)nullptr,
                                              (float*)nullptr, (float*)nullptr, 1600, 6, 6, 0, 2);

    (void)in_sizes; (void)n_in; (void)out_size; (void)ws_size;
}